// Round 4
// baseline (501.730 us; speedup 1.0000x reference)
//
#include <hip/hip_runtime.h>
#include <stdint.h>

// VQVAE quantise, fp32 in/out.
// R4: R3 geometry (split-S, 2 blocks/CU) + lazy store drain. The per-iter
// __syncthreads forced vmcnt(0), draining the NT one-hot zero-stores
// (HBM write-ack) on every iteration's critical path — that was R3's
// regression. Replaced with the verified raw-barrier idiom
// (s_waitcnt lgkmcnt(0) + sched_barrier + s_barrier): LDS double-buffer
// only needs lgkmcnt; NT stores drain lazily across iterations and are
// ordered vs finalize's 1.0-write by the kernel boundary.
// Distance math / tie-break unchanged from the passing baseline.

#define B_SZ 256
#define C_SZ 64
#define E_SZ 128
#define S_SZ 4096
#define CW   8192
#define TS   64    // s-rows per tile
#define LDB  136   // LDS B-row stride in f16

typedef __attribute__((ext_vector_type(4))) float    float4a;
typedef __attribute__((ext_vector_type(8))) _Float16 half8;

__device__ __forceinline__ void split8(float4a f0, float4a f1, half8& hi, half8& lo) {
    #pragma unroll
    for (int j = 0; j < 4; ++j) {
        _Float16 h0 = (_Float16)f0[j];
        hi[j]     = h0;
        lo[j]     = (_Float16)(f0[j] - (float)h0);
        _Float16 h1 = (_Float16)f1[j];
        hi[4 + j] = h1;
        lo[4 + j] = (_Float16)(f1[j] - (float)h1);
    }
}

// LDS-only barrier: does NOT drain vmcnt (NT stores keep flowing).
__device__ __forceinline__ void barrier_lds_only() {
    asm volatile("s_waitcnt lgkmcnt(0)" ::: "memory");
    __builtin_amdgcn_sched_barrier(0);
    __builtin_amdgcn_s_barrier();
    __builtin_amdgcn_sched_barrier(0);
}

// grid 512 = (shalf 0..1) x (btile 0..3) x (c 0..63), block 512 = 8 waves.
__global__ __launch_bounds__(512, 4) void argmin_mfma(
    const float* __restrict__ x,
    const float* __restrict__ dict,
    float* __restrict__ cw_out,
    float* __restrict__ oh)
{
    __shared__ __attribute__((aligned(16))) _Float16 bh[2][TS * LDB];  // 2x17 KB
    __shared__ __attribute__((aligned(16))) _Float16 bl[2][TS * LDB];  // 2x17 KB
    __shared__ float dsqp[2][TS][8];                                   // 4 KB
    // final reduction tables aliased onto staging LDS (used after the loop)
    float* rv = reinterpret_cast<float*>(bh);   // 64*64 floats = 16 KB
    int*   ri = reinterpret_cast<int*>(bl);     // 64*64 ints   = 16 KB

    const int tid   = threadIdx.x;
    const int lane  = tid & 63;
    const int quad  = lane >> 4;
    const int l15   = lane & 15;
    const int wid   = tid >> 6;
    const int mhalf = wid & 1;
    const int nquad = wid >> 1;
    const int c     = blockIdx.x & 63;
    const int btile = (blockIdx.x >> 6) & 3;
    const int shalf = blockIdx.x >> 8;
    const int sbase = shalf * 2048;

    // ---- runtime layout probes: true (row, col) of each (lane, reg) ----
    int m_attr[4], n_attr[4];
    {
        half8 ones, enc;
        #pragma unroll
        for (int j = 0; j < 8; ++j) { ones[j] = (_Float16)1.0f; enc[j] = (_Float16)(float)l15; }
        float4a z = {0.f, 0.f, 0.f, 0.f};
        float4a pr = __builtin_amdgcn_mfma_f32_16x16x32_f16(enc, ones, z, 0, 0, 0);
        float4a pc = __builtin_amdgcn_mfma_f32_16x16x32_f16(ones, enc, z, 0, 0, 0);
        #pragma unroll
        for (int r = 0; r < 4; ++r) {
            m_attr[r] = (int)(pr[r] * 0.03125f + 0.5f);   // row feeding this element
            n_attr[r] = (int)(pc[r] * 0.03125f + 0.5f);   // col feeding this element
        }
    }

    // ---- A fragments (regs, whole kernel): loader believes A[m=l15][k=kk*32+quad*8+j] ----
    half8 ah[2][4], al[2][4];
    #pragma unroll
    for (int mi = 0; mi < 2; ++mi) {
        int b = btile * 64 + mhalf * 32 + mi * 16 + l15;
        const float* xr = x + (size_t)b * CW + c * E_SZ;
        #pragma unroll
        for (int kk = 0; kk < 4; ++kk) {
            float4a f0 = *reinterpret_cast<const float4a*>(xr + kk * 32 + quad * 8);
            float4a f1 = *reinterpret_cast<const float4a*>(xr + kk * 32 + quad * 8 + 4);
            split8(f0, f1, ah[mi][kk], al[mi][kk]);
        }
    }

    // ---- staging coords (fixed per thread): 64 rows x 128 f32, 16 f32/thread ----
    const int srow = tid >> 3;
    const int kq   = (tid & 7) * 16;
    const float* drow = dict + ((size_t)c * S_SZ + sbase + srow) * E_SZ + kq;

    // ---- one-hot base for this block: rows (btile*64 + r, c), s in [sbase, sbase+2048) ----
    float* ohb = oh + ((size_t)(btile * 64) * C_SZ + c) * S_SZ + sbase;
    const size_t oh_bstride = (size_t)C_SZ * S_SZ;   // stride between consecutive b

    // ---- prologue: load + convert tile 0 into buffer 0 ----
    float4a pf[4];
    #pragma unroll
    for (int ck = 0; ck < 4; ++ck)
        pf[ck] = *reinterpret_cast<const float4a*>(drow + ck * 4);
    {
        float dp = 0.f;
        #pragma unroll
        for (int ck = 0; ck < 2; ++ck) {
            half8 h, l;
            split8(pf[2 * ck], pf[2 * ck + 1], h, l);
            #pragma unroll
            for (int j = 0; j < 4; ++j) {
                dp = fmaf(pf[2 * ck][j], pf[2 * ck][j], dp);
                dp = fmaf(pf[2 * ck + 1][j], pf[2 * ck + 1][j], dp);
            }
            *reinterpret_cast<half8*>(&bh[0][srow * LDB + kq + ck * 8]) = h;
            *reinterpret_cast<half8*>(&bl[0][srow * LDB + kq + ck * 8]) = l;
        }
        dsqp[0][srow][tid & 7] = dp;
    }

    float bestv[8];
    int   besti[8];
    #pragma unroll
    for (int i = 0; i < 8; ++i) { bestv[i] = 3.4e38f; besti[i] = 0; }

    __syncthreads();

    int cur = 0;
    for (int it = 0; it < 32; ++it) {
        // ---- issue next tile's global loads FIRST (so the convert-phase
        //      wait for them need not drain the younger zero-stores) ----
        if (it + 1 < 32) {
            const float* dr = drow + (size_t)(it + 1) * (TS * E_SZ);
            #pragma unroll
            for (int ck = 0; ck < 4; ++ck)
                pf[ck] = *reinterpret_cast<const float4a*>(dr + ck * 4);
        }

        // ---- zero 2 of this block's 64 half-rows (never vmcnt-drained
        //      in-loop: they ride idle HBM BW and retire lazily) ----
        {
            float4a zz = {0.f, 0.f, 0.f, 0.f};
            float* z0 = ohb + (size_t)(it * 2) * oh_bstride;
            float* z1 = z0 + oh_bstride;
            __builtin_nontemporal_store(zz, reinterpret_cast<float4a*>(z0) + tid);
            __builtin_nontemporal_store(zz, reinterpret_cast<float4a*>(z1) + tid);
        }

        // ---- MFMA phase on buf[cur] ----
        const _Float16* bhc = bh[cur];
        const _Float16* blc = bl[cur];
        float4a acc[2] = {{0.f,0.f,0.f,0.f},{0.f,0.f,0.f,0.f}};
        __builtin_amdgcn_s_setprio(1);
        #pragma unroll
        for (int kk = 0; kk < 4; ++kk) {
            const int sl = nquad * 16 + l15;   // loader believes col = l15
            half8 bhf = *reinterpret_cast<const half8*>(bhc + sl * LDB + kk * 32 + quad * 8);
            half8 blf = *reinterpret_cast<const half8*>(blc + sl * LDB + kk * 32 + quad * 8);
            #pragma unroll
            for (int mi = 0; mi < 2; ++mi) {
                acc[mi] = __builtin_amdgcn_mfma_f32_16x16x32_f16(
                    ah[mi][kk], bhf, acc[mi], 0, 0, 0);
                acc[mi] = __builtin_amdgcn_mfma_f32_16x16x32_f16(
                    ah[mi][kk], blf, acc[mi], 0, 0, 0);
                acc[mi] = __builtin_amdgcn_mfma_f32_16x16x32_f16(
                    al[mi][kk], bhf, acc[mi], 0, 0, 0);
            }
        }
        __builtin_amdgcn_s_setprio(0);

        // ---- epilogue: dist = d_sq - 2*cross (x_sq const per (b,c): argmin-invariant) ----
        #pragma unroll
        for (int r = 0; r < 4; ++r) {
            const int sl = nquad * 16 + n_attr[r];   // true col attribution
            float4a qa = *reinterpret_cast<const float4a*>(&dsqp[cur][sl][0]);
            float4a qb = *reinterpret_cast<const float4a*>(&dsqp[cur][sl][4]);
            float dsq = ((qa[0] + qa[1]) + (qa[2] + qa[3]))
                      + ((qb[0] + qb[1]) + (qb[2] + qb[3]));
            int sg = sbase + it * TS + sl;
            #pragma unroll
            for (int mi = 0; mi < 2; ++mi) {
                float dist = dsq - 2.0f * acc[mi][r];
                int slot = mi * 4 + r;
                if (dist < bestv[slot]) { bestv[slot] = dist; besti[slot] = sg; }
            }
        }

        // ---- convert prefetched tile into buf[cur^1] ----
        if (it + 1 < 32) {
            const int nb = cur ^ 1;
            float dp = 0.f;
            #pragma unroll
            for (int ck = 0; ck < 2; ++ck) {
                half8 h, l;
                split8(pf[2 * ck], pf[2 * ck + 1], h, l);
                #pragma unroll
                for (int j = 0; j < 4; ++j) {
                    dp = fmaf(pf[2 * ck][j], pf[2 * ck][j], dp);
                    dp = fmaf(pf[2 * ck + 1][j], pf[2 * ck + 1][j], dp);
                }
                *reinterpret_cast<half8*>(&bh[nb][srow * LDB + kq + ck * 8]) = h;
                *reinterpret_cast<half8*>(&bl[nb][srow * LDB + kq + ck * 8]) = l;
            }
            dsqp[nb][srow][tid & 7] = dp;
        }
        barrier_lds_only();   // LDS ordering only; NT stores NOT drained
        cur ^= 1;
    }

    // all waves' LDS reads retired before the last barrier; safe to alias rv/ri

    // ---- dump: bijective 64x64 scatter using true (row,col) attribution ----
    #pragma unroll
    for (int mi = 0; mi < 2; ++mi)
        #pragma unroll
        for (int r = 0; r < 4; ++r) {
            int row = mhalf * 32 + mi * 16 + m_attr[r];
            int col = nquad * 16 + n_attr[r];
            rv[row * 64 + col] = bestv[mi * 4 + r];
            ri[row * 64 + col] = besti[mi * 4 + r];
        }
    barrier_lds_only();

    if (tid < 64) {
        float bv = 3.4e38f; int bi = 0x7fffffff;
        for (int j = 0; j < 64; ++j) {
            float v = rv[tid * 64 + j];
            int   i = ri[tid * 64 + j];
            if (v < bv || (v == bv && i < bi)) { bv = v; bi = i; }  // first-occurrence tie
        }
        // park (dist, idx) candidate in the cw_out cell this (btile,c)'s
        // finalize block reads-then-overwrites. shalf slots are disjoint.
        float* cp = cw_out + (size_t)(btile * 64 + tid) * CW + c * E_SZ + shalf * 2;
        cp[0] = bv;
        cp[1] = __int_as_float(bi);
    }
    // kernel end drains all outstanding NT zero-stores before finalize runs
}

// grid 256 = (btile, c), 256 threads: combine 2 candidates per row, write the
// one-hot 1.0, gather cw_embed (overwrites the candidate slab after reading).
__global__ __launch_bounds__(256) void finalize(
    const float* __restrict__ dict,
    float* __restrict__ cw_out,
    float* __restrict__ oh)
{
    __shared__ int fid[64];
    const int c     = blockIdx.x & 63;
    const int btile = blockIdx.x >> 6;
    const int tid   = threadIdx.x;

    if (tid < 64) {
        const float* cp = cw_out + (size_t)(btile * 64 + tid) * CW + c * E_SZ;
        float d0 = cp[0]; int i0 = __float_as_int(cp[1]);
        float d1 = cp[2]; int i1 = __float_as_int(cp[3]);
        // i0 < 2048 <= i1 always: strict d1<d0 preserves first-occurrence tie
        int bi = (d1 < d0) ? i1 : i0;
        fid[tid] = bi;
        oh[((size_t)(btile * 64 + tid) * C_SZ + c) * S_SZ + bi] = 1.0f;
    }
    __syncthreads();

    // gather: 64 rows x 32 float4, 4 threads/row x 8 float4 each
    const int row = tid >> 2, q = tid & 3;
    const int bi = fid[row];
    const float4a* src = reinterpret_cast<const float4a*>(
        dict + ((size_t)c * S_SZ + bi) * E_SZ) + q * 8;
    float4a* dst = reinterpret_cast<float4a*>(
        cw_out + (size_t)(btile * 64 + row) * CW + c * E_SZ) + q * 8;
    #pragma unroll
    for (int j = 0; j < 8; ++j) dst[j] = src[j];
}

extern "C" void kernel_launch(void* const* d_in, const int* in_sizes, int n_in,
                              void* d_out, int out_size, void* d_ws, size_t ws_size,
                              hipStream_t stream) {
    const float* x    = (const float*)d_in[0];
    const float* dict = (const float*)d_in[1];
    float* out = (float*)d_out;
    float* oh  = out + (size_t)B_SZ * CW;

    argmin_mfma<<<dim3(512), dim3(512), 0, stream>>>(x, dict, out, oh);
    finalize<<<dim3(256), dim3(256), 0, stream>>>(dict, out, oh);
}

// Round 5
// 451.529 us; speedup vs baseline: 1.1112x; 1.1112x over previous
//
#include <hip/hip_runtime.h>
#include <stdint.h>

// VQVAE quantise, fp32 in/out.
// R5: revert to R2 structure (grid 256, 1 block/CU, 128-row dict tiles,
// fused one-hot zeroing + in-kernel ending — best measured at 198 us) with
// ONE isolated change: LDS bank-conflict fix. LDB 136->128 plus XOR swizzle
// f16_idx ^= (row&7)<<3 (byte bits 4-6) applied identically on staging
// writes and fragment reads. Old layout put ~8 lanes per 4-bank group on
// both ds_write_b128 and ds_read_b128 (SQ_LDS_BANK_CONFLICT 1.05e7); the
// swizzle makes both sides 2 lanes/bank (free per m136).
// R3/R4 lesson kept: vmcnt retires in order, so in-loop NT stores drain at
// the next load-wait no matter the barrier idiom -> plain __syncthreads.
// Distance math / MFMA order / tie-break bit-identical to passing baseline.

#define B_SZ 256
#define C_SZ 64
#define E_SZ 128
#define S_SZ 4096
#define CW   8192
#define LDB  128   // LDS B-row stride in f16 (swizzled, no pad)

typedef __attribute__((ext_vector_type(4))) float    float4a;
typedef __attribute__((ext_vector_type(8))) _Float16 half8;

__device__ __forceinline__ int swz(int row, int cf16) {
    return row * LDB + (cf16 ^ ((row & 7) << 3));
}

__device__ __forceinline__ void split8(float4a f0, float4a f1, half8& hi, half8& lo) {
    #pragma unroll
    for (int j = 0; j < 4; ++j) {
        _Float16 h0 = (_Float16)f0[j];
        hi[j]     = h0;
        lo[j]     = (_Float16)(f0[j] - (float)h0);
        _Float16 h1 = (_Float16)f1[j];
        hi[4 + j] = h1;
        lo[4 + j] = (_Float16)(f1[j] - (float)h1);
    }
}

// grid 256 = (btile 0..3) x (c 0..63), block 512 = 8 waves (mhalf x nquad).
__global__ __launch_bounds__(512, 2) void argmin_mfma(
    const float* __restrict__ x,
    const float* __restrict__ dict,
    float* __restrict__ cw_out,
    float* __restrict__ oh)
{
    __shared__ __attribute__((aligned(16))) _Float16 bh[2][128 * LDB];  // 2x32 KB
    __shared__ __attribute__((aligned(16))) _Float16 bl[2][128 * LDB];  // 2x32 KB
    __shared__ float4a dsqp[2][128];
    __shared__ int     fid[64];
    // final reduction tables aliased onto staging LDS (used after the loop)
    float* rv = reinterpret_cast<float*>(bh);   // 64*64 floats = 16 KB
    int*   ri = reinterpret_cast<int*>(bl);     // 64*64 ints   = 16 KB

    const int tid   = threadIdx.x;
    const int lane  = tid & 63;
    const int quad  = lane >> 4;
    const int l15   = lane & 15;
    const int wid   = tid >> 6;
    const int mhalf = wid & 1;
    const int nquad = wid >> 1;
    const int c     = blockIdx.x & 63;
    const int btile = blockIdx.x >> 6;

    // ---- runtime layout probes: true (row, col) of each (lane, reg) ----
    int m_attr[4], n_attr[4];
    {
        half8 ones, enc;
        #pragma unroll
        for (int j = 0; j < 8; ++j) { ones[j] = (_Float16)1.0f; enc[j] = (_Float16)(float)l15; }
        float4a z = {0.f, 0.f, 0.f, 0.f};
        float4a pr = __builtin_amdgcn_mfma_f32_16x16x32_f16(enc, ones, z, 0, 0, 0);
        float4a pc = __builtin_amdgcn_mfma_f32_16x16x32_f16(ones, enc, z, 0, 0, 0);
        #pragma unroll
        for (int r = 0; r < 4; ++r) {
            m_attr[r] = (int)(pr[r] * 0.03125f + 0.5f);   // row feeding this element
            n_attr[r] = (int)(pc[r] * 0.03125f + 0.5f);   // col feeding this element
        }
    }

    // ---- A fragments (regs, whole kernel): loader believes A[m=l15][k=kk*32+quad*8+j] ----
    half8 ah[2][4], al[2][4];
    #pragma unroll
    for (int mi = 0; mi < 2; ++mi) {
        int b = btile * 64 + mhalf * 32 + mi * 16 + l15;
        const float* xr = x + (size_t)b * CW + c * E_SZ;
        #pragma unroll
        for (int kk = 0; kk < 4; ++kk) {
            float4a f0 = *reinterpret_cast<const float4a*>(xr + kk * 32 + quad * 8);
            float4a f1 = *reinterpret_cast<const float4a*>(xr + kk * 32 + quad * 8 + 4);
            split8(f0, f1, ah[mi][kk], al[mi][kk]);
        }
    }

    // ---- staging coords (fixed per thread) ----
    const int srow = tid >> 2;
    const int kq   = (tid & 3) * 32;
    const int q4   = tid & 3;
    const float* drow = dict + ((size_t)c * S_SZ + srow) * E_SZ + kq;

    // ---- one-hot base for this block: rows (btile*64 + r, c) ----
    float* ohb = oh + ((size_t)(btile * 64) * C_SZ + c) * S_SZ;
    const size_t oh_bstride = (size_t)C_SZ * S_SZ;   // stride between consecutive b

    // ---- prologue: load + convert tile 0 into buffer 0 ----
    float4a pf0[4], pf1[4];
    #pragma unroll
    for (int ck = 0; ck < 4; ++ck) {
        pf0[ck] = *reinterpret_cast<const float4a*>(drow + ck * 8);
        pf1[ck] = *reinterpret_cast<const float4a*>(drow + ck * 8 + 4);
    }
    {
        float dp = 0.f;
        #pragma unroll
        for (int ck = 0; ck < 4; ++ck) {
            half8 h, l;
            split8(pf0[ck], pf1[ck], h, l);
            #pragma unroll
            for (int j = 0; j < 4; ++j) {
                dp = fmaf(pf0[ck][j], pf0[ck][j], dp);
                dp = fmaf(pf1[ck][j], pf1[ck][j], dp);
            }
            *reinterpret_cast<half8*>(&bh[0][swz(srow, kq + ck * 8)]) = h;
            *reinterpret_cast<half8*>(&bl[0][swz(srow, kq + ck * 8)]) = l;
        }
        dsqp[0][srow][q4] = dp;
    }

    float bestv[8];
    int   besti[8];
    #pragma unroll
    for (int i = 0; i < 8; ++i) { bestv[i] = 3.4e38f; besti[i] = 0; }

    __syncthreads();

    int cur = 0;
    for (int it = 0; it < 32; ++it) {
        const int s0 = it * 128;

        // ---- issue next tile's global loads (latency hides under MFMA) ----
        if (it + 1 < 32) {
            const float* dr = drow + (size_t)(it + 1) * (128 * E_SZ);
            #pragma unroll
            for (int ck = 0; ck < 4; ++ck) {
                pf0[ck] = *reinterpret_cast<const float4a*>(dr + ck * 8);
                pf1[ck] = *reinterpret_cast<const float4a*>(dr + ck * 8 + 4);
            }
        }

        // ---- zero 2 of this block's 64 one-hot rows (NT stores drain by the
        //      next load-wait; in-order vmcnt makes that unavoidable) ----
        {
            float4a zz = {0.f, 0.f, 0.f, 0.f};
            float* z0 = ohb + (size_t)(it * 2) * oh_bstride;
            float* z1 = z0 + oh_bstride;
            __builtin_nontemporal_store(zz, reinterpret_cast<float4a*>(z0) + tid);
            __builtin_nontemporal_store(zz, reinterpret_cast<float4a*>(z0) + 512 + tid);
            __builtin_nontemporal_store(zz, reinterpret_cast<float4a*>(z1) + tid);
            __builtin_nontemporal_store(zz, reinterpret_cast<float4a*>(z1) + 512 + tid);
        }

        // ---- MFMA phase on buf[cur] ----
        const _Float16* bhc = bh[cur];
        const _Float16* blc = bl[cur];
        float4a acc[2][2] = {{{0.f,0.f,0.f,0.f},{0.f,0.f,0.f,0.f}},
                             {{0.f,0.f,0.f,0.f},{0.f,0.f,0.f,0.f}}};
        __builtin_amdgcn_s_setprio(1);
        #pragma unroll
        for (int kk = 0; kk < 4; ++kk) {
            half8 bhf[2], blf[2];
            #pragma unroll
            for (int ni = 0; ni < 2; ++ni) {
                const int sl = nquad * 32 + ni * 16 + l15;   // loader believes col = l15
                bhf[ni] = *reinterpret_cast<const half8*>(bhc + swz(sl, kk * 32 + quad * 8));
                blf[ni] = *reinterpret_cast<const half8*>(blc + swz(sl, kk * 32 + quad * 8));
            }
            #pragma unroll
            for (int mi = 0; mi < 2; ++mi)
                #pragma unroll
                for (int ni = 0; ni < 2; ++ni) {
                    acc[mi][ni] = __builtin_amdgcn_mfma_f32_16x16x32_f16(
                        ah[mi][kk], bhf[ni], acc[mi][ni], 0, 0, 0);
                    acc[mi][ni] = __builtin_amdgcn_mfma_f32_16x16x32_f16(
                        ah[mi][kk], blf[ni], acc[mi][ni], 0, 0, 0);
                    acc[mi][ni] = __builtin_amdgcn_mfma_f32_16x16x32_f16(
                        al[mi][kk], bhf[ni], acc[mi][ni], 0, 0, 0);
                }
        }
        __builtin_amdgcn_s_setprio(0);

        // ---- epilogue: dist = d_sq - 2*cross (x_sq const per (b,c): argmin-invariant) ----
        #pragma unroll
        for (int ni = 0; ni < 2; ++ni)
            #pragma unroll
            for (int r = 0; r < 4; ++r) {
                const int sl = nquad * 32 + ni * 16 + n_attr[r];   // true col attribution
                float4a q4v = dsqp[cur][sl];
                float dsq = (q4v[0] + q4v[1]) + (q4v[2] + q4v[3]);
                int sg = s0 + sl;
                #pragma unroll
                for (int mi = 0; mi < 2; ++mi) {
                    float dist = dsq - 2.0f * acc[mi][ni][r];
                    int slot = mi * 4 + r;
                    if (dist < bestv[slot]) { bestv[slot] = dist; besti[slot] = sg; }
                }
            }

        // ---- convert prefetched tile into buf[cur^1] ----
        if (it + 1 < 32) {
            const int nb = cur ^ 1;
            float dp = 0.f;
            #pragma unroll
            for (int ck = 0; ck < 4; ++ck) {
                half8 h, l;
                split8(pf0[ck], pf1[ck], h, l);
                #pragma unroll
                for (int j = 0; j < 4; ++j) {
                    dp = fmaf(pf0[ck][j], pf0[ck][j], dp);
                    dp = fmaf(pf1[ck][j], pf1[ck][j], dp);
                }
                *reinterpret_cast<half8*>(&bh[nb][swz(srow, kq + ck * 8)]) = h;
                *reinterpret_cast<half8*>(&bl[nb][swz(srow, kq + ck * 8)]) = l;
            }
            dsqp[nb][srow][q4] = dp;
        }
        __syncthreads();   // LDS ordering + drains NT zero-stores (in-order vmcnt)
        cur ^= 1;
    }

    // loop-end barrier: all LDS reads done (alias rv/ri) and all 64 one-hot
    // rows of this block are zeroed & drained.

    // ---- dump: bijective 64x64 scatter using true (row,col) attribution ----
    #pragma unroll
    for (int mi = 0; mi < 2; ++mi)
        #pragma unroll
        for (int r = 0; r < 4; ++r) {
            int row = mhalf * 32 + mi * 16 + m_attr[r];
            int col = nquad * 16 + n_attr[r];
            rv[row * 64 + col] = bestv[mi * 4 + r];
            ri[row * 64 + col] = besti[mi * 4 + r];
        }
    __syncthreads();

    if (tid < 64) {
        float bv = 3.4e38f; int bi = 0x7fffffff;
        for (int j = 0; j < 64; ++j) {
            float v = rv[tid * 64 + j];
            int   i = ri[tid * 64 + j];
            if (v < bv || (v == bv && i < bi)) { bv = v; bi = i; }  // first-occurrence tie
        }
        fid[tid] = bi;
        // zero-stores to this row completed at the last loop barrier
        ohb[(size_t)tid * oh_bstride + bi] = 1.0f;
    }
    __syncthreads();

    // ---- gather cw_embed: 64 rows x 32 float4 chunks ----
    for (int u = tid; u < 64 * 32; u += 512) {
        int row = u >> 5, ch = u & 31;
        int bi = fid[row];
        float4a v = *reinterpret_cast<const float4a*>(
            dict + ((size_t)c * S_SZ + bi) * E_SZ + ch * 4);
        *reinterpret_cast<float4a*>(
            cw_out + (size_t)(btile * 64 + row) * CW + c * E_SZ + ch * 4) = v;
    }
}

extern "C" void kernel_launch(void* const* d_in, const int* in_sizes, int n_in,
                              void* d_out, int out_size, void* d_ws, size_t ws_size,
                              hipStream_t stream) {
    const float* x    = (const float*)d_in[0];
    const float* dict = (const float*)d_in[1];
    float* out = (float*)d_out;
    float* oh  = out + (size_t)B_SZ * CW;

    argmin_mfma<<<dim3(256), dim3(512), 0, stream>>>(x, dict, out, oh);
}

// Round 6
// 437.266 us; speedup vs baseline: 1.1474x; 1.0326x over previous
//
#include <hip/hip_runtime.h>
#include <stdint.h>

// VQVAE quantise, fp32 in/out.
// R6: delivery-volume fix. Re-block the grid as (squad over S, c): each
// block computes ALL 256 x-rows vs a 1024-code dict slice, so every dict
// byte is delivered to exactly ONE CU (512 MB -> 134 MB of L3->CU traffic,
// the R2-R5 wall at ~4.3 TB/s fabric rate). 4x arithmetic intensity per
// staged tile (M=256). x lives in registers (mi=4 per wave, 8 waves =
// 4 mq x 2 nh). Per-(b,c) argmin spans 4 blocks -> 4 candidates parked in
// cw_out, combined in finalize (squads s-ordered, strict < keeps exact
// first-occurrence ties). One-hot zeroing: block zeroes its s-quarter of
// all 256 rows (same total bytes, rides on idle write BW).
// Per-element distance math / split8 / MFMA sequence unchanged.

#define B_SZ 256
#define C_SZ 64
#define E_SZ 128
#define S_SZ 4096
#define CW   8192
#define TS   64     // dict rows staged per iter
#define SPB  1024   // S-range per block
#define LDB  128    // LDS B-row stride in f16 (swizzled)

typedef __attribute__((ext_vector_type(4))) float    float4a;
typedef __attribute__((ext_vector_type(8))) _Float16 half8;

__device__ __forceinline__ int swz(int row, int cf16) {
    return row * LDB + (cf16 ^ ((row & 7) << 3));
}

__device__ __forceinline__ void split8(float4a f0, float4a f1, half8& hi, half8& lo) {
    #pragma unroll
    for (int j = 0; j < 4; ++j) {
        _Float16 h0 = (_Float16)f0[j];
        hi[j]     = h0;
        lo[j]     = (_Float16)(f0[j] - (float)h0);
        _Float16 h1 = (_Float16)f1[j];
        hi[4 + j] = h1;
        lo[4 + j] = (_Float16)(f1[j] - (float)h1);
    }
}

// grid 256 = (squad 0..3) x (c 0..63), block 512 = 8 waves (mq 0..3, nh 0..1).
__global__ __launch_bounds__(512, 2) void argmin_mfma(
    const float* __restrict__ x,
    const float* __restrict__ dict,
    float* __restrict__ cw_out,
    float* __restrict__ oh)
{
    __shared__ __attribute__((aligned(16))) _Float16 bh[2][TS * LDB];  // 2x16 KB
    __shared__ __attribute__((aligned(16))) _Float16 bl[2][TS * LDB];  // 2x16 KB
    __shared__ __attribute__((aligned(16))) float dsqp[2][TS][8];      // 4 KB
    // final reduction tables aliased onto staging LDS (used after the loop)
    float* rv = reinterpret_cast<float*>(bh);   // 32 cols x 256 rows = 32 KB
    int*   ri = reinterpret_cast<int*>(bl);     // 32 KB

    const int tid   = threadIdx.x;
    const int lane  = tid & 63;
    const int quad  = lane >> 4;
    const int l15   = lane & 15;
    const int wid   = tid >> 6;
    const int mq    = wid & 3;
    const int nh    = wid >> 2;
    const int c     = blockIdx.x & 63;
    const int squad = blockIdx.x >> 6;
    const int sbase = squad * SPB;

    // ---- runtime layout probes: true (row, col) of each (lane, reg) ----
    int m_attr[4], n_attr[4];
    {
        half8 ones, enc;
        #pragma unroll
        for (int j = 0; j < 8; ++j) { ones[j] = (_Float16)1.0f; enc[j] = (_Float16)(float)l15; }
        float4a z = {0.f, 0.f, 0.f, 0.f};
        float4a pr = __builtin_amdgcn_mfma_f32_16x16x32_f16(enc, ones, z, 0, 0, 0);
        float4a pc = __builtin_amdgcn_mfma_f32_16x16x32_f16(ones, enc, z, 0, 0, 0);
        #pragma unroll
        for (int r = 0; r < 4; ++r) {
            m_attr[r] = (int)(pr[r] * 0.03125f + 0.5f);   // row feeding this element
            n_attr[r] = (int)(pc[r] * 0.03125f + 0.5f);   // col feeding this element
        }
    }

    // ---- A fragments (regs, whole kernel): wave mq owns rows [mq*64, mq*64+64) ----
    half8 ah[4][4], al[4][4];
    #pragma unroll
    for (int mi = 0; mi < 4; ++mi) {
        int b = mq * 64 + mi * 16 + l15;
        const float* xr = x + (size_t)b * CW + c * E_SZ;
        #pragma unroll
        for (int kk = 0; kk < 4; ++kk) {
            float4a f0 = *reinterpret_cast<const float4a*>(xr + kk * 32 + quad * 8);
            float4a f1 = *reinterpret_cast<const float4a*>(xr + kk * 32 + quad * 8 + 4);
            split8(f0, f1, ah[mi][kk], al[mi][kk]);
        }
    }

    // ---- staging coords: 64 rows x 128 f32, 16 f32/thread ----
    const int srow = tid >> 3;
    const int kq   = (tid & 7) * 16;
    const int q8   = tid & 7;
    const float* drow = dict + ((size_t)c * S_SZ + sbase + srow) * E_SZ + kq;

    // ---- prologue: load + convert tile 0 into buffer 0 ----
    float4a pf[4];
    #pragma unroll
    for (int ck = 0; ck < 4; ++ck)
        pf[ck] = *reinterpret_cast<const float4a*>(drow + ck * 4);
    {
        float dp = 0.f;
        #pragma unroll
        for (int ck = 0; ck < 2; ++ck) {
            half8 h, l;
            split8(pf[2 * ck], pf[2 * ck + 1], h, l);
            #pragma unroll
            for (int j = 0; j < 4; ++j) {
                dp = fmaf(pf[2 * ck][j], pf[2 * ck][j], dp);
                dp = fmaf(pf[2 * ck + 1][j], pf[2 * ck + 1][j], dp);
            }
            *reinterpret_cast<half8*>(&bh[0][swz(srow, kq + ck * 8)]) = h;
            *reinterpret_cast<half8*>(&bl[0][swz(srow, kq + ck * 8)]) = l;
        }
        dsqp[0][srow][q8] = dp;
    }

    float bestv[16];
    int   besti[16];
    #pragma unroll
    for (int i = 0; i < 16; ++i) { bestv[i] = 3.4e38f; besti[i] = 0; }

    __syncthreads();

    int cur = 0;
    for (int it = 0; it < 16; ++it) {
        // ---- issue next tile's global loads FIRST (oldest in vmcnt queue:
        //      the convert-phase load-wait won't require store retirement) ----
        if (it + 1 < 16) {
            const float* dr = drow + (size_t)(it + 1) * (TS * E_SZ);
            #pragma unroll
            for (int ck = 0; ck < 4; ++ck)
                pf[ck] = *reinterpret_cast<const float4a*>(dr + ck * 4);
        }

        // ---- zero 16 of the 256 one-hot row-slices (s in [sbase,sbase+1024)) ----
        {
            const int zrow = it * 16 + (tid >> 5);
            const int t5   = tid & 31;
            float* zb = oh + ((size_t)zrow * C_SZ + c) * S_SZ + sbase;
            float4a zz = {0.f, 0.f, 0.f, 0.f};
            #pragma unroll
            for (int j = 0; j < 8; ++j)
                __builtin_nontemporal_store(zz, reinterpret_cast<float4a*>(zb) + t5 + j * 32);
        }

        // ---- MFMA phase on buf[cur]: 96 MFMAs/wave ----
        const _Float16* bhc = bh[cur];
        const _Float16* blc = bl[cur];
        float4a acc[4][2] = {{{0.f,0.f,0.f,0.f},{0.f,0.f,0.f,0.f}},
                             {{0.f,0.f,0.f,0.f},{0.f,0.f,0.f,0.f}},
                             {{0.f,0.f,0.f,0.f},{0.f,0.f,0.f,0.f}},
                             {{0.f,0.f,0.f,0.f},{0.f,0.f,0.f,0.f}}};
        __builtin_amdgcn_s_setprio(1);
        #pragma unroll
        for (int kk = 0; kk < 4; ++kk) {
            half8 bhf[2], blf[2];
            #pragma unroll
            for (int ni = 0; ni < 2; ++ni) {
                const int sl = nh * 32 + ni * 16 + l15;   // loader believes col = l15
                bhf[ni] = *reinterpret_cast<const half8*>(bhc + swz(sl, kk * 32 + quad * 8));
                blf[ni] = *reinterpret_cast<const half8*>(blc + swz(sl, kk * 32 + quad * 8));
            }
            #pragma unroll
            for (int mi = 0; mi < 4; ++mi)
                #pragma unroll
                for (int ni = 0; ni < 2; ++ni) {
                    acc[mi][ni] = __builtin_amdgcn_mfma_f32_16x16x32_f16(
                        ah[mi][kk], bhf[ni], acc[mi][ni], 0, 0, 0);
                    acc[mi][ni] = __builtin_amdgcn_mfma_f32_16x16x32_f16(
                        ah[mi][kk], blf[ni], acc[mi][ni], 0, 0, 0);
                    acc[mi][ni] = __builtin_amdgcn_mfma_f32_16x16x32_f16(
                        al[mi][kk], bhf[ni], acc[mi][ni], 0, 0, 0);
                }
        }
        __builtin_amdgcn_s_setprio(0);

        // ---- epilogue: dist = d_sq - 2*cross (x_sq const per (b,c): argmin-invariant) ----
        #pragma unroll
        for (int ni = 0; ni < 2; ++ni)
            #pragma unroll
            for (int r = 0; r < 4; ++r) {
                const int sl = nh * 32 + ni * 16 + n_attr[r];   // true col attribution
                float4a qa = *reinterpret_cast<const float4a*>(&dsqp[cur][sl][0]);
                float4a qb = *reinterpret_cast<const float4a*>(&dsqp[cur][sl][4]);
                float dsq = ((qa[0] + qa[1]) + (qa[2] + qa[3]))
                          + ((qb[0] + qb[1]) + (qb[2] + qb[3]));
                int sg = sbase + it * TS + sl;
                #pragma unroll
                for (int mi = 0; mi < 4; ++mi) {
                    float dist = dsq - 2.0f * acc[mi][ni][r];
                    int slot = mi * 4 + r;
                    if (dist < bestv[slot]) { bestv[slot] = dist; besti[slot] = sg; }
                }
            }

        // ---- convert prefetched tile into buf[cur^1] ----
        if (it + 1 < 16) {
            const int nb = cur ^ 1;
            float dp = 0.f;
            #pragma unroll
            for (int ck = 0; ck < 2; ++ck) {
                half8 h, l;
                split8(pf[2 * ck], pf[2 * ck + 1], h, l);
                #pragma unroll
                for (int j = 0; j < 4; ++j) {
                    dp = fmaf(pf[2 * ck][j], pf[2 * ck][j], dp);
                    dp = fmaf(pf[2 * ck + 1][j], pf[2 * ck + 1][j], dp);
                }
                *reinterpret_cast<half8*>(&bh[nb][swz(srow, kq + ck * 8)]) = h;
                *reinterpret_cast<half8*>(&bl[nb][swz(srow, kq + ck * 8)]) = l;
            }
            dsqp[nb][srow][q8] = dp;
        }
        __syncthreads();
        cur ^= 1;
    }

    // loop-end barrier: all LDS reads done (alias rv/ri); this block's
    // s-quarter of all 256 one-hot rows is zeroed.

    // ---- dump: bijective (row 0..255) x (col 0..31) scatter, transposed
    //      (rv[col*256+row]) so the scan below is bank-conflict-free ----
    #pragma unroll
    for (int mi = 0; mi < 4; ++mi)
        #pragma unroll
        for (int r = 0; r < 4; ++r) {
            int row = mq * 64 + mi * 16 + m_attr[r];
            int col = nh * 16 + n_attr[r];
            rv[col * 256 + row] = bestv[mi * 4 + r];
            ri[col * 256 + row] = besti[mi * 4 + r];
        }
    __syncthreads();

    if (tid < 256) {
        float bv = 3.4e38f; int bi = 0x7fffffff;
        #pragma unroll 4
        for (int j = 0; j < 32; ++j) {
            float v = rv[j * 256 + tid];
            int   i = ri[j * 256 + tid];
            if (v < bv || (v == bv && i < bi)) { bv = v; bi = i; }  // first-occurrence tie
        }
        // park (dist, idx) in the cw_out cell finalize reads-then-overwrites;
        // squad slots (2 floats each) are disjoint.
        float* cp = cw_out + (size_t)tid * CW + c * E_SZ + squad * 2;
        cp[0] = bv;
        cp[1] = __int_as_float(bi);
    }
    // kernel end drains all NT zero-stores before finalize runs
}

// grid 256 = (btile, c), 256 threads: combine 4 s-quarter candidates per row,
// write the one-hot 1.0, gather cw_embed (overwrites the candidate slab).
__global__ __launch_bounds__(256) void finalize(
    const float* __restrict__ dict,
    float* __restrict__ cw_out,
    float* __restrict__ oh)
{
    __shared__ int fid[64];
    const int c     = blockIdx.x & 63;
    const int btile = blockIdx.x >> 6;
    const int tid   = threadIdx.x;

    if (tid < 64) {
        const int row = btile * 64 + tid;
        const float* cp = cw_out + (size_t)row * CW + c * E_SZ;
        float bv = cp[0]; int bi = __float_as_int(cp[1]);
        #pragma unroll
        for (int k = 1; k < 4; ++k) {
            float v = cp[2 * k];
            // squads are s-ordered: strict < preserves global first-occurrence
            if (v < bv) { bv = v; bi = __float_as_int(cp[2 * k + 1]); }
        }
        fid[tid] = bi;
        oh[((size_t)row * C_SZ + c) * S_SZ + bi] = 1.0f;
    }
    __syncthreads();

    // gather: 64 rows x 32 float4, 4 threads/row x 8 float4 each
    const int row = tid >> 2, q = tid & 3;
    const int bi = fid[row];
    const float4a* src = reinterpret_cast<const float4a*>(
        dict + ((size_t)c * S_SZ + bi) * E_SZ) + q * 8;
    float4a* dst = reinterpret_cast<float4a*>(
        cw_out + (size_t)(btile * 64 + row) * CW + c * E_SZ) + q * 8;
    #pragma unroll
    for (int j = 0; j < 8; ++j) dst[j] = src[j];
}

extern "C" void kernel_launch(void* const* d_in, const int* in_sizes, int n_in,
                              void* d_out, int out_size, void* d_ws, size_t ws_size,
                              hipStream_t stream) {
    const float* x    = (const float*)d_in[0];
    const float* dict = (const float*)d_in[1];
    float* out = (float*)d_out;
    float* oh  = out + (size_t)B_SZ * CW;

    argmin_mfma<<<dim3(256), dim3(512), 0, stream>>>(x, dict, out, oh);
    finalize<<<dim3(256), dim3(256), 0, stream>>>(dict, out, oh);
}